// Round 3
// baseline (263.362 us; speedup 1.0000x reference)
//
#include <hip/hip_runtime.h>

// EfficientAdditiveAttention  B=8, L=512, D=128
//
// combined(q,k) = sum_d w_all[d]*tanh(zq_d + zk_d)  -> softmax_k -> @V
// Key identity: tanh(a+b) = (tanh a + tanh b)/(1 + tanh a * tanh b).
// Proj kernel precomputes Tq=tanh(zq), Tk=tanh(zk), WTq=w~*Tq (w~ = log2e*w_all),
// so the O(B*L*L*D) hot loop has NO exp at all:
//   per d-pair: d_i = fma(Tq,Tk,1); n_i = fma(w~,Tk,WTq);
//   s += (n1*d2 + n2*d1) * rcp(d1*d2)         [8 VALU + 1 rcp / 2 elements]
// p = exp2(s) directly (log2e folded into w~); constant biases are
// softmax-invariant and dropped. No max-subtraction needed (|s| bounded).

#define BB 8
#define LL 512
#define DD 128
#define NROW (BB*LL)            // 4096 rows
#define MATN (NROW*DD)          // 524288 elements per matrix

static constexpr float C1 = 2.8853900817779268f;    // 2*log2(e): exp2(C1*z) = e^{2z}
static constexpr float LOG2E = 1.4426950408889634f;
static constexpr float INV_SCALE = 0.08838834764831845f; // 1/sqrt(128)

__device__ __forceinline__ float fast_exp2(float x) { return __builtin_amdgcn_exp2f(x); }
__device__ __forceinline__ float fast_rcp(float x)  { return __builtin_amdgcn_rcpf(x); }

// ---------------------------------------------------------------------------
// Projection: z = X @ W.T + b; outputs Tq=tanh(z),WTq (m=0), Tk=tanh(z) (m=1),
// V=z (m=2). 32-row x 128-col tiles, 384 blocks x 256 threads.
// ---------------------------------------------------------------------------
__global__ __launch_bounds__(256) void proj_kernel(
    const float* __restrict__ query, const float* __restrict__ key,
    const float* __restrict__ value,
    const float* __restrict__ Wq, const float* __restrict__ bq,
    const float* __restrict__ Wk, const float* __restrict__ bk,
    const float* __restrict__ Wv, const float* __restrict__ bv,
    const float* __restrict__ wd, const float* __restrict__ wsg,
    const float* __restrict__ wtt, float* __restrict__ ws)
{
    __shared__ __align__(16) float Wl[128 * 66];   // 33792 B
    __shared__ __align__(16) float Xl[32 * 66];    //  8448 B

    const int bx = blockIdx.x;
    const int m  = bx >> 7;              // 0:Q 1:K 2:V  (128 row-tiles each)
    const int r0 = (bx & 127) * 32;
    const float* X    = (m == 0) ? query : (m == 1) ? key : value;
    const float* W    = (m == 0) ? Wq    : (m == 1) ? Wk  : Wv;
    const float* bias = (m == 0) ? bq    : (m == 1) ? bk  : bv;
    const int t = threadIdx.x;

    // w~ = log2e * (1/sqrt(D) + wd + wsg + wtt)  -> ws tail (block 0)
    if (bx == 0 && t < 128) {
        ws[(size_t)4 * MATN + t] = LOG2E * (INV_SCALE + wd[t] + wsg[t] + wtt[t]);
    }

    const int cg = t & 31;   // cols: cg + 32*j
    const int rg = t >> 5;   // rows: rg*4 + i

    float acc[4][4];
    #pragma unroll
    for (int j = 0; j < 4; ++j) {
        float bj = bias[cg + 32 * j];
        #pragma unroll
        for (int i = 0; i < 4; ++i) acc[i][j] = bj;
    }

    const float4* Wsrc = (const float4*)W;
    const float4* Xsrc = (const float4*)X;

    for (int h = 0; h < 2; ++h) {            // K-dim halves (64 each)
        __syncthreads();
        #pragma unroll
        for (int j = 0; j < 8; ++j) {        // W half: 128 rows x 16 f4
            int g = t + j * 256;
            int c = g >> 4, f4 = g & 15;
            float4 v = Wsrc[c * 32 + h * 16 + f4];
            float* dst = &Wl[c * 66 + f4 * 4];
            *(float2*)dst       = make_float2(v.x, v.y);
            *(float2*)(dst + 2) = make_float2(v.z, v.w);
        }
        #pragma unroll
        for (int j = 0; j < 2; ++j) {        // X half: 32 rows x 16 f4
            int g = t + j * 256;
            int r = g >> 4, f4 = g & 15;
            float4 v = Xsrc[(r0 + r) * 32 + h * 16 + f4];
            float* dst = &Xl[r * 66 + f4 * 4];
            *(float2*)dst       = make_float2(v.x, v.y);
            *(float2*)(dst + 2) = make_float2(v.z, v.w);
        }
        __syncthreads();

        #pragma unroll 4
        for (int dg = 0; dg < 32; ++dg) {
            float2 bf[4];
            #pragma unroll
            for (int j = 0; j < 4; ++j)
                bf[j] = *(const float2*)&Wl[(cg + 32 * j) * 66 + 2 * dg];
            float2 af[4];
            #pragma unroll
            for (int i = 0; i < 4; ++i)
                af[i] = *(const float2*)&Xl[(rg * 4 + i) * 66 + 2 * dg];
            #pragma unroll
            for (int i = 0; i < 4; ++i)
                #pragma unroll
                for (int j = 0; j < 4; ++j)
                    acc[i][j] += af[i].x * bf[j].x + af[i].y * bf[j].y;
        }
    }

    if (m == 0) {
        float* oT = ws;                     // Tq
        float* oW = ws + (size_t)MATN;      // WTq = w~ * Tq
        float wc[4];
        #pragma unroll
        for (int j = 0; j < 4; ++j) {
            int c = cg + 32 * j;
            wc[j] = LOG2E * (INV_SCALE + wd[c] + wsg[c] + wtt[c]);
        }
        #pragma unroll
        for (int i = 0; i < 4; ++i) {
            int r = r0 + rg * 4 + i;
            #pragma unroll
            for (int j = 0; j < 4; ++j) {
                float z = acc[i][j];
                float e = fast_exp2(C1 * z);
                float tt2 = (e - 1.0f) * fast_rcp(e + 1.0f);   // tanh(z)
                oT[(size_t)r * DD + cg + 32 * j] = tt2;
                oW[(size_t)r * DD + cg + 32 * j] = wc[j] * tt2;
            }
        }
    } else if (m == 1) {
        float* oK = ws + (size_t)2 * MATN;  // Tk
        #pragma unroll
        for (int i = 0; i < 4; ++i) {
            int r = r0 + rg * 4 + i;
            #pragma unroll
            for (int j = 0; j < 4; ++j) {
                float z = acc[i][j];
                float e = fast_exp2(C1 * z);
                oK[(size_t)r * DD + cg + 32 * j] = (e - 1.0f) * fast_rcp(e + 1.0f);
            }
        }
    } else {
        float* oV = ws + (size_t)3 * MATN;  // V
        #pragma unroll
        for (int i = 0; i < 4; ++i) {
            int r = r0 + rg * 4 + i;
            #pragma unroll
            for (int j = 0; j < 4; ++j)
                oV[(size_t)r * DD + cg + 32 * j] = acc[i][j];
        }
    }
}

// ---------------------------------------------------------------------------
// Attention. 256 blocks x 512 threads; block = 16 q-rows, wave = 2 q-rows.
// Per 32-k tile: stage Tk->[k][130] (padded, conflict-free b64), V->[k][128].
// Pass A: lane = (k = lane&31, d-half = lane>>5); K-quad register-cached and
// reused for both q; Q-side (Tq,WTq,w~) via wave-uniform s_loads (scalar pipe,
// off the LDS pipe). Cross-half combine: 1 shfl_xor(32) per q.
// Pass B fused per tile: lane = d-pair; wave reads its own Pt rows (no
// cross-wave traffic, no barrier between A and B). 35 KB LDS -> 4 blocks/CU.
// ---------------------------------------------------------------------------
__global__ __launch_bounds__(512, 8) void attn_kernel(
    const float* __restrict__ ws, float* __restrict__ out)
{
    __shared__ __align__(16) float Tkt[32 * 130];   // 16640 B
    __shared__ __align__(16) float Vt[32 * 128];    // 16384 B
    __shared__ __align__(16) float Pt[16 * 32];     //  2048 B

    const float* Tq  = ws;
    const float* WTq = ws + (size_t)MATN;
    const float* Tk  = ws + (size_t)2 * MATN;
    const float* Vp  = ws + (size_t)3 * MATN;
    const float* wtl = ws + (size_t)4 * MATN;

    const int bx   = blockIdx.x;               // 256 blocks
    const int b    = bx >> 5;                  // 32 blocks per batch
    const int wave = __builtin_amdgcn_readfirstlane((int)threadIdx.x >> 6);
    const int lane = threadIdx.x & 63;
    const int qa   = bx * 16 + 2 * wave;       // wave-uniform

    const float4* __restrict__ TqA = (const float4*)(Tq  + (size_t)qa * DD);
    const float4* __restrict__ WqA = (const float4*)(WTq + (size_t)qa * DD);
    const float4* __restrict__ TqB = (const float4*)(Tq  + (size_t)(qa + 1) * DD);
    const float4* __restrict__ WqB = (const float4*)(WTq + (size_t)(qa + 1) * DD);
    const float4* __restrict__ W4  = (const float4*)wtl;
    const float* __restrict__ Tkb = Tk + (size_t)b * (LL * DD);
    const float* __restrict__ Vb  = Vp + (size_t)b * (LL * DD);

    const int k  = lane & 31;
    const int dh = lane >> 5;
    const int d2 = 2 * lane;

    float oax = 0.f, oay = 0.f, obx = 0.f, oby = 0.f;
    float ps0 = 0.f, ps1 = 0.f;

    for (int tt = 0; tt < 16; ++tt) {
        __syncthreads();
        {   // ---- stage: Tk 1024 f4 + V 1024 f4, 2+2 per thread
            const float4* sK = (const float4*)(Tkb + (size_t)tt * 32 * DD);
            const float4* sV = (const float4*)(Vb  + (size_t)tt * 32 * DD);
            #pragma unroll
            for (int j = 0; j < 2; ++j) {
                int gg = threadIdx.x + j * 512;
                int kk = gg >> 5, c4 = gg & 31;
                float4 v = sK[gg];
                float* dst = &Tkt[kk * 130 + c4 * 4];
                *(float2*)dst       = make_float2(v.x, v.y);
                *(float2*)(dst + 2) = make_float2(v.z, v.w);
            }
            #pragma unroll
            for (int j = 0; j < 2; ++j) {
                int gg = threadIdx.x + j * 512;
                ((float4*)Vt)[gg] = sV[gg];
            }
        }
        __syncthreads();

        // ---- pass A: s(qa, k), s(qa+1, k) over this lane's 64 d's
        float s0 = 0.f, s1 = 0.f;
        {
            const float* kr = &Tkt[k * 130 + dh * 64];
            const int qoff = dh * 16;
            #pragma unroll 4
            for (int i = 0; i < 16; ++i) {
                float4 w  = W4 [qoff + i];      // uniform -> s_load
                float4 ta = TqA[qoff + i];
                float4 wa = WqA[qoff + i];
                float4 tb = TqB[qoff + i];
                float4 wb = WqB[qoff + i];
                float2 k01 = *(const float2*)(kr + 4 * i);
                float2 k23 = *(const float2*)(kr + 4 * i + 2);
                // q = qa, pair (0,1)
                {
                    float e1 = fmaf(ta.x, k01.x, 1.f), e2 = fmaf(ta.y, k01.y, 1.f);
                    float n1 = fmaf(w.x, k01.x, wa.x), n2 = fmaf(w.y, k01.y, wa.y);
                    float N  = fmaf(n1, e2, n2 * e1);
                    s0 = fmaf(N, fast_rcp(e1 * e2), s0);
                }
                // q = qa, pair (2,3)
                {
                    float e1 = fmaf(ta.z, k23.x, 1.f), e2 = fmaf(ta.w, k23.y, 1.f);
                    float n1 = fmaf(w.z, k23.x, wa.z), n2 = fmaf(w.w, k23.y, wa.w);
                    float N  = fmaf(n1, e2, n2 * e1);
                    s0 = fmaf(N, fast_rcp(e1 * e2), s0);
                }
                // q = qa+1, pair (0,1)
                {
                    float e1 = fmaf(tb.x, k01.x, 1.f), e2 = fmaf(tb.y, k01.y, 1.f);
                    float n1 = fmaf(w.x, k01.x, wb.x), n2 = fmaf(w.y, k01.y, wb.y);
                    float N  = fmaf(n1, e2, n2 * e1);
                    s1 = fmaf(N, fast_rcp(e1 * e2), s1);
                }
                // q = qa+1, pair (2,3)
                {
                    float e1 = fmaf(tb.z, k23.x, 1.f), e2 = fmaf(tb.w, k23.y, 1.f);
                    float n1 = fmaf(w.z, k23.x, wb.z), n2 = fmaf(w.w, k23.y, wb.w);
                    float N  = fmaf(n1, e2, n2 * e1);
                    s1 = fmaf(N, fast_rcp(e1 * e2), s1);
                }
            }
        }
        s0 += __shfl_xor(s0, 32);
        s1 += __shfl_xor(s1, 32);
        float p0 = fast_exp2(s0);
        float p1 = fast_exp2(s1);
        Pt[(2 * wave) * 32 + k]     = p0;   // both halves write same value
        Pt[(2 * wave + 1) * 32 + k] = p1;
        ps0 += p0;                           // double-counted; halved at end
        ps1 += p1;

        // ---- pass B (same-wave Pt handoff; no barrier needed)
        const float* prow0 = &Pt[(2 * wave) * 32];
        const float* prow1 = prow0 + 32;
        #pragma unroll
        for (int kq = 0; kq < 8; ++kq) {
            float4 pa = *(const float4*)(prow0 + 4 * kq);   // bcast
            float4 pb = *(const float4*)(prow1 + 4 * kq);
            #pragma unroll
            for (int j = 0; j < 4; ++j) {
                float2 v = *(const float2*)&Vt[(4 * kq + j) * 128 + d2];
                float paj = ((const float*)&pa)[j];
                float pbj = ((const float*)&pb)[j];
                oax = fmaf(paj, v.x, oax); oay = fmaf(paj, v.y, oay);
                obx = fmaf(pbj, v.x, obx); oby = fmaf(pbj, v.y, oby);
            }
        }
    }

    #pragma unroll
    for (int off = 32; off; off >>= 1) {
        ps0 += __shfl_xor(ps0, off);
        ps1 += __shfl_xor(ps1, off);
    }
    float inv0 = fast_rcp(0.5f * ps0);   // undo the 2x double count
    float inv1 = fast_rcp(0.5f * ps1);
    *(float2*)&out[(size_t)qa * DD + d2]       = make_float2(oax * inv0, oay * inv0);
    *(float2*)&out[(size_t)(qa + 1) * DD + d2] = make_float2(obx * inv1, oby * inv1);
}

// ---------------------------------------------------------------------------
extern "C" void kernel_launch(void* const* d_in, const int* in_sizes, int n_in,
                              void* d_out, int out_size, void* d_ws, size_t ws_size,
                              hipStream_t stream) {
    const float* query = (const float*)d_in[0];
    const float* key_  = (const float*)d_in[1];
    const float* value = (const float*)d_in[2];
    const float* Wq    = (const float*)d_in[3];
    const float* bq    = (const float*)d_in[4];
    const float* Wk    = (const float*)d_in[5];
    const float* bk    = (const float*)d_in[6];
    const float* Wv    = (const float*)d_in[7];
    const float* bv    = (const float*)d_in[8];
    const float* wd    = (const float*)d_in[9];
    // d_in[10]/[12]/[14] = b_delta/b_sigma/b_theta: softmax-invariant, dropped
    const float* wsg   = (const float*)d_in[11];
    const float* wtt   = (const float*)d_in[13];
    float* ws = (float*)d_ws;   // 4*MATN + 128 floats ~ 8.4 MB

    proj_kernel<<<384, 256, 0, stream>>>(query, key_, value,
                                         Wq, bq, Wk, bk, Wv, bv,
                                         wd, wsg, wtt, ws);
    attn_kernel<<<256, 512, 0, stream>>>(ws, (float*)d_out);
}

// Round 4
// 167.346 us; speedup vs baseline: 1.5738x; 1.5738x over previous
//
#include <hip/hip_runtime.h>

// EfficientAdditiveAttention  B=8, L=512, D=128
//
// combined(q,k) = sum_d w_all[d]*tanh(zq_d + zk_d)  -> softmax_k -> @V
// tanh(a+b) = (Ta+Tk)/(1+Ta*Tk); proj precomputes Tq, WTq=w~*Tq, Tk, V
// (w~ = log2e*w_all). Hot loop per d-pair (per q):
//   u_j = w~_j*Tk_j (shared over 4 q); e_j = fma(Tq,Tk,1); t_j = WTq_j + u_j;
//   s += (t0*e1 + t1*e0) * rcp(e0*e1)
// p = exp2(s) directly; constant biases are softmax-invariant and dropped.
//
// Structure (v4): LDS-BW-bound -> amortize tile reads over 4 q-rows/wave.
// 512 blocks x 256 thr; block = (16 q) x (k-half: 4 tiles of 64 k), fused
// score+PV per tile. Partial o/psum combined via f32 atomics into zeroed
// buffers; small normalize kernel divides at the end.

#define BB 8
#define LL 512
#define DD 128
#define NROW (BB*LL)            // 4096 rows
#define MATN (NROW*DD)          // 524288 elements per matrix

static constexpr float C1 = 2.8853900817779268f;    // 2*log2(e)
static constexpr float LOG2E = 1.4426950408889634f;
static constexpr float INV_SCALE = 0.08838834764831845f; // 1/sqrt(128)

__device__ __forceinline__ float fast_exp2(float x) { return __builtin_amdgcn_exp2f(x); }
__device__ __forceinline__ float fast_rcp(float x)  { return __builtin_amdgcn_rcpf(x); }

// ---------------------------------------------------------------------------
// Projection: z = X @ W.T + b; outputs Tq=tanh(z),WTq (m=0), Tk=tanh(z) (m=1),
// V=z (m=2). 32-row x 128-col tiles, 384 blocks x 256 threads.  (validated R3)
// ---------------------------------------------------------------------------
__global__ __launch_bounds__(256) void proj_kernel(
    const float* __restrict__ query, const float* __restrict__ key,
    const float* __restrict__ value,
    const float* __restrict__ Wq, const float* __restrict__ bq,
    const float* __restrict__ Wk, const float* __restrict__ bk,
    const float* __restrict__ Wv, const float* __restrict__ bv,
    const float* __restrict__ wd, const float* __restrict__ wsg,
    const float* __restrict__ wtt, float* __restrict__ ws)
{
    __shared__ __align__(16) float Wl[128 * 66];   // 33792 B
    __shared__ __align__(16) float Xl[32 * 66];    //  8448 B

    const int bx = blockIdx.x;
    const int m  = bx >> 7;              // 0:Q 1:K 2:V  (128 row-tiles each)
    const int r0 = (bx & 127) * 32;
    const float* X    = (m == 0) ? query : (m == 1) ? key : value;
    const float* W    = (m == 0) ? Wq    : (m == 1) ? Wk  : Wv;
    const float* bias = (m == 0) ? bq    : (m == 1) ? bk  : bv;
    const int t = threadIdx.x;

    // w~ = log2e * (1/sqrt(D) + wd + wsg + wtt)  -> ws tail (block 0)
    if (bx == 0 && t < 128) {
        ws[(size_t)4 * MATN + t] = LOG2E * (INV_SCALE + wd[t] + wsg[t] + wtt[t]);
    }

    const int cg = t & 31;   // cols: cg + 32*j
    const int rg = t >> 5;   // rows: rg*4 + i

    float acc[4][4];
    #pragma unroll
    for (int j = 0; j < 4; ++j) {
        float bj = bias[cg + 32 * j];
        #pragma unroll
        for (int i = 0; i < 4; ++i) acc[i][j] = bj;
    }

    const float4* Wsrc = (const float4*)W;
    const float4* Xsrc = (const float4*)X;

    for (int h = 0; h < 2; ++h) {            // K-dim halves (64 each)
        __syncthreads();
        #pragma unroll
        for (int j = 0; j < 8; ++j) {        // W half: 128 rows x 16 f4
            int g = t + j * 256;
            int c = g >> 4, f4 = g & 15;
            float4 v = Wsrc[c * 32 + h * 16 + f4];
            float* dst = &Wl[c * 66 + f4 * 4];
            *(float2*)dst       = make_float2(v.x, v.y);
            *(float2*)(dst + 2) = make_float2(v.z, v.w);
        }
        #pragma unroll
        for (int j = 0; j < 2; ++j) {        // X half: 32 rows x 16 f4
            int g = t + j * 256;
            int r = g >> 4, f4 = g & 15;
            float4 v = Xsrc[(r0 + r) * 32 + h * 16 + f4];
            float* dst = &Xl[r * 66 + f4 * 4];
            *(float2*)dst       = make_float2(v.x, v.y);
            *(float2*)(dst + 2) = make_float2(v.z, v.w);
        }
        __syncthreads();

        #pragma unroll 4
        for (int dg = 0; dg < 32; ++dg) {
            float2 bf[4];
            #pragma unroll
            for (int j = 0; j < 4; ++j)
                bf[j] = *(const float2*)&Wl[(cg + 32 * j) * 66 + 2 * dg];
            float2 af[4];
            #pragma unroll
            for (int i = 0; i < 4; ++i)
                af[i] = *(const float2*)&Xl[(rg * 4 + i) * 66 + 2 * dg];
            #pragma unroll
            for (int i = 0; i < 4; ++i)
                #pragma unroll
                for (int j = 0; j < 4; ++j)
                    acc[i][j] += af[i].x * bf[j].x + af[i].y * bf[j].y;
        }
    }

    if (m == 0) {
        float* oT = ws;                     // Tq
        float* oW = ws + (size_t)MATN;      // WTq = w~ * Tq
        float wc[4];
        #pragma unroll
        for (int j = 0; j < 4; ++j) {
            int c = cg + 32 * j;
            wc[j] = LOG2E * (INV_SCALE + wd[c] + wsg[c] + wtt[c]);
        }
        #pragma unroll
        for (int i = 0; i < 4; ++i) {
            int r = r0 + rg * 4 + i;
            #pragma unroll
            for (int j = 0; j < 4; ++j) {
                float z = acc[i][j];
                float e = fast_exp2(C1 * z);
                float th = (e - 1.0f) * fast_rcp(e + 1.0f);   // tanh(z)
                oT[(size_t)r * DD + cg + 32 * j] = th;
                oW[(size_t)r * DD + cg + 32 * j] = wc[j] * th;
            }
        }
    } else if (m == 1) {
        float* oK = ws + (size_t)2 * MATN;  // Tk
        #pragma unroll
        for (int i = 0; i < 4; ++i) {
            int r = r0 + rg * 4 + i;
            #pragma unroll
            for (int j = 0; j < 4; ++j) {
                float z = acc[i][j];
                float e = fast_exp2(C1 * z);
                oK[(size_t)r * DD + cg + 32 * j] = (e - 1.0f) * fast_rcp(e + 1.0f);
            }
        }
    } else {
        float* oV = ws + (size_t)3 * MATN;  // V
        #pragma unroll
        for (int i = 0; i < 4; ++i) {
            int r = r0 + rg * 4 + i;
            #pragma unroll
            for (int j = 0; j < 4; ++j)
                oV[(size_t)r * DD + cg + 32 * j] = acc[i][j];
        }
    }
}

// ---------------------------------------------------------------------------
// Attention main. 512 blocks x 256 threads (4 waves). Block = 16 q x k-half.
// Wave = 4 consecutive q-rows. Per 64-k tile (4 per block): stage Tk->[k][130]
// (2-way-free banks), V->[k][128]; pass A lane-owns-k over ALL 128 d (Q-side
// addresses fully wave-uniform -> s_load scalar pipe); fused pass B via
// per-wave Pt rows (same-wave handoff, no barrier). Partial o/psum -> atomics.
// ---------------------------------------------------------------------------
__global__ __launch_bounds__(256) void attn_kernel(
    const float* __restrict__ ws, float* __restrict__ out,
    float* __restrict__ psumG)
{
    __shared__ __align__(16) float Tkt[64 * 130];   // 33280 B
    __shared__ __align__(16) float Vt[64 * 128];    // 32768 B
    __shared__ __align__(16) float Pt[4 * 4 * 64];  //  4096 B

    const float* Tq  = ws;
    const float* WTq = ws + (size_t)MATN;
    const float* Tk  = ws + (size_t)2 * MATN;
    const float* Vp  = ws + (size_t)3 * MATN;
    const float4* W4 = (const float4*)(ws + (size_t)4 * MATN);

    const int bx   = blockIdx.x;               // 512 blocks
    const int qblk = bx >> 1;                  // 0..255  (16 q each)
    const int kx   = bx & 1;                   // k-half
    const int b    = qblk >> 5;                // 32 q-blocks per batch
    const int wave = __builtin_amdgcn_readfirstlane((int)threadIdx.x >> 6);
    const int lane = threadIdx.x & 63;
    const int qa   = qblk * 16 + wave * 4;     // wave-uniform

    const float4* __restrict__ Tq4 = (const float4*)Tq;
    const float4* __restrict__ Wq4 = (const float4*)WTq;
    const float* __restrict__ Tkb = Tk + (size_t)b * (LL * DD);
    const float* __restrict__ Vb  = Vp + (size_t)b * (LL * DD);

    float2 o[4];
    float ps[4];
    #pragma unroll
    for (int qq = 0; qq < 4; ++qq) { o[qq] = make_float2(0.f, 0.f); ps[qq] = 0.f; }

    float* PtW = &Pt[wave * 256];
    const int d2 = 2 * lane;

    for (int j = 0; j < 4; ++j) {
        const int tt = kx * 4 + j;
        __syncthreads();
        {   // stage Tk (scattered f2, stride 130) + V ([k][128] linear)
            const float4* sK = (const float4*)(Tkb + (size_t)tt * 64 * DD);
            const float4* sV = (const float4*)(Vb  + (size_t)tt * 64 * DD);
            #pragma unroll
            for (int r = 0; r < 8; ++r) {
                int g = threadIdx.x + r * 256;     // 0..2047
                int row = g >> 5, c4 = g & 31;
                float4 v = sK[g];
                float* dst = &Tkt[row * 130 + c4 * 4];
                *(float2*)dst       = make_float2(v.x, v.y);
                *(float2*)(dst + 2) = make_float2(v.z, v.w);
            }
            #pragma unroll
            for (int r = 0; r < 8; ++r) {
                int g = threadIdx.x + r * 256;
                ((float4*)Vt)[g] = sV[g];
            }
        }
        __syncthreads();

        // ---- pass A: s(qa..qa+3, k=lane) over all 128 d
        float s0 = 0.f, s1 = 0.f, s2 = 0.f, s3 = 0.f;
        const float* krow = &Tkt[lane * 130];
        #pragma unroll 2
        for (int i = 0; i < 32; ++i) {
            float4 w   = W4[i];                         // uniform -> s_load
            float2 k01 = *(const float2*)(krow + 4 * i);
            float2 k23 = *(const float2*)(krow + 4 * i + 2);
            float u0 = w.x * k01.x, u1 = w.y * k01.y;
            float u2 = w.z * k23.x, u3 = w.w * k23.y;
            #define QTERM(SS, QQ) { \
                float4 tq = Tq4[(size_t)(qa + QQ) * 32 + i]; \
                float4 aq = Wq4[(size_t)(qa + QQ) * 32 + i]; \
                float e0 = fmaf(tq.x, k01.x, 1.f), e1 = fmaf(tq.y, k01.y, 1.f); \
                float e2 = fmaf(tq.z, k23.x, 1.f), e3 = fmaf(tq.w, k23.y, 1.f); \
                float t0 = aq.x + u0, t1 = aq.y + u1; \
                float t2 = aq.z + u2, t3 = aq.w + u3; \
                float N01 = fmaf(t0, e1, t1 * e0); \
                float N23 = fmaf(t2, e3, t3 * e2); \
                SS = fmaf(N01, fast_rcp(e0 * e1), SS); \
                SS = fmaf(N23, fast_rcp(e2 * e3), SS); }
            QTERM(s0, 0) QTERM(s1, 1) QTERM(s2, 2) QTERM(s3, 3)
            #undef QTERM
        }
        float p0 = fast_exp2(s0), p1 = fast_exp2(s1);
        float p2 = fast_exp2(s2), p3 = fast_exp2(s3);
        PtW[lane]       = p0;
        PtW[64  + lane] = p1;
        PtW[128 + lane] = p2;
        PtW[192 + lane] = p3;
        ps[0] += p0; ps[1] += p1; ps[2] += p2; ps[3] += p3;

        // ---- pass B (same-wave Pt handoff; lane = d-pair)
        #pragma unroll 4
        for (int kk = 0; kk < 16; ++kk) {
            float4 pa = *(const float4*)&PtW[4 * kk];         // bcast
            float4 pb = *(const float4*)&PtW[64  + 4 * kk];
            float4 pc = *(const float4*)&PtW[128 + 4 * kk];
            float4 pd = *(const float4*)&PtW[192 + 4 * kk];
            #pragma unroll
            for (int e = 0; e < 4; ++e) {
                float2 v = *(const float2*)&Vt[(4 * kk + e) * 128 + d2];
                float fa = ((const float*)&pa)[e];
                float fb = ((const float*)&pb)[e];
                float fc = ((const float*)&pc)[e];
                float fd = ((const float*)&pd)[e];
                o[0].x = fmaf(fa, v.x, o[0].x); o[0].y = fmaf(fa, v.y, o[0].y);
                o[1].x = fmaf(fb, v.x, o[1].x); o[1].y = fmaf(fb, v.y, o[1].y);
                o[2].x = fmaf(fc, v.x, o[2].x); o[2].y = fmaf(fc, v.y, o[2].y);
                o[3].x = fmaf(fd, v.x, o[3].x); o[3].y = fmaf(fd, v.y, o[3].y);
            }
        }
    }

    // psum: each lane holds the sum over its k's (distinct across lanes)
    #pragma unroll
    for (int off = 32; off; off >>= 1) {
        ps[0] += __shfl_xor(ps[0], off);
        ps[1] += __shfl_xor(ps[1], off);
        ps[2] += __shfl_xor(ps[2], off);
        ps[3] += __shfl_xor(ps[3], off);
    }
    if (lane == 0) {
        atomicAdd(&psumG[qa + 0], ps[0]);
        atomicAdd(&psumG[qa + 1], ps[1]);
        atomicAdd(&psumG[qa + 2], ps[2]);
        atomicAdd(&psumG[qa + 3], ps[3]);
    }
    #pragma unroll
    for (int qq = 0; qq < 4; ++qq) {
        atomicAdd(&out[(size_t)(qa + qq) * DD + d2],     o[qq].x);
        atomicAdd(&out[(size_t)(qa + qq) * DD + d2 + 1], o[qq].y);
    }
}

// ---------------------------------------------------------------------------
__global__ __launch_bounds__(256) void norm_kernel(
    float* __restrict__ out, const float* __restrict__ psumG)
{
    int t = blockIdx.x * 256 + threadIdx.x;    // 262144 float2s
    float2* o2 = (float2*)out;
    int q = t >> 6;
    float inv = fast_rcp(psumG[q]);
    float2 v = o2[t];
    o2[t] = make_float2(v.x * inv, v.y * inv);
}

// ---------------------------------------------------------------------------
extern "C" void kernel_launch(void* const* d_in, const int* in_sizes, int n_in,
                              void* d_out, int out_size, void* d_ws, size_t ws_size,
                              hipStream_t stream) {
    const float* query = (const float*)d_in[0];
    const float* key_  = (const float*)d_in[1];
    const float* value = (const float*)d_in[2];
    const float* Wq    = (const float*)d_in[3];
    const float* bq    = (const float*)d_in[4];
    const float* Wk    = (const float*)d_in[5];
    const float* bk    = (const float*)d_in[6];
    const float* Wv    = (const float*)d_in[7];
    const float* bv    = (const float*)d_in[8];
    const float* wd    = (const float*)d_in[9];
    // d_in[10]/[12]/[14] = b_delta/b_sigma/b_theta: softmax-invariant, dropped
    const float* wsg   = (const float*)d_in[11];
    const float* wtt   = (const float*)d_in[13];
    float* ws = (float*)d_ws;   // 4*MATN + 128 + 4096 floats ~ 8.4 MB
    float* psumG = ws + (size_t)4 * MATN + 128;
    float* out = (float*)d_out;

    hipMemsetAsync(out, 0, (size_t)out_size * sizeof(float), stream);
    hipMemsetAsync(psumG, 0, (size_t)NROW * sizeof(float), stream);
    proj_kernel<<<384, 256, 0, stream>>>(query, key_, value,
                                         Wq, bq, Wk, bk, Wv, bv,
                                         wd, wsg, wtt, ws);
    attn_kernel<<<512, 256, 0, stream>>>(ws, out, psumG);
    norm_kernel<<<1024, 256, 0, stream>>>(out, psumG);
}

// Round 5
// 159.795 us; speedup vs baseline: 1.6481x; 1.0473x over previous
//
#include <hip/hip_runtime.h>

// EfficientAdditiveAttention  B=8, L=512, D=128
//
// combined(q,k) = sum_d w_all[d]*tanh(zq_d + zk_d)  -> softmax_k -> @V
// tanh(a+b) = (Ta+Tk)/(1+Ta*Tk); proj precomputes Tq, WTq=w~*Tq, Tk, V
// (w~ = log2e*w_all). Hot loop per d-pair per q:
//   e_j = fma(Tq,Tk,1); t_j = WTq_j + u_j (u=w~*Tk shared over 4 q);
//   s += (t0*e1 + t1*e0) * rcp(e0*e1)        [8 VALU + 1 rcp / 2 elements]
// p = exp2(s); constant biases are softmax-invariant and dropped.
//
// v5: R4 showed VALU work ~= 28 us but 58% idle (2 blocks/CU, 8 waves/CU).
// -> V read from global in pass B (LDS 70->41.5 KB), 512x512 blocks
// (8 waves, 32 q, k quartered), launch_bounds(512,4) to keep 2 blocks/CU
// resident = 16 waves/CU. Partials via f32 atomics + normalize kernel.

#define BB 8
#define LL 512
#define DD 128
#define NROW (BB*LL)            // 4096 rows
#define MATN (NROW*DD)          // 524288 elements per matrix

static constexpr float C1 = 2.8853900817779268f;    // 2*log2(e)
static constexpr float LOG2E = 1.4426950408889634f;
static constexpr float INV_SCALE = 0.08838834764831845f; // 1/sqrt(128)

__device__ __forceinline__ float fast_exp2(float x) { return __builtin_amdgcn_exp2f(x); }
__device__ __forceinline__ float fast_rcp(float x)  { return __builtin_amdgcn_rcpf(x); }

// ---------------------------------------------------------------------------
// Projection: z = X @ W.T + b; outputs Tq=tanh(z),WTq (m=0), Tk=tanh(z) (m=1),
// V=z (m=2). 32-row x 128-col tiles, 384 blocks x 256 threads.  (validated R3/R4)
// ---------------------------------------------------------------------------
__global__ __launch_bounds__(256) void proj_kernel(
    const float* __restrict__ query, const float* __restrict__ key,
    const float* __restrict__ value,
    const float* __restrict__ Wq, const float* __restrict__ bq,
    const float* __restrict__ Wk, const float* __restrict__ bk,
    const float* __restrict__ Wv, const float* __restrict__ bv,
    const float* __restrict__ wd, const float* __restrict__ wsg,
    const float* __restrict__ wtt, float* __restrict__ ws)
{
    __shared__ __align__(16) float Wl[128 * 66];   // 33792 B
    __shared__ __align__(16) float Xl[32 * 66];    //  8448 B

    const int bx = blockIdx.x;
    const int m  = bx >> 7;              // 0:Q 1:K 2:V  (128 row-tiles each)
    const int r0 = (bx & 127) * 32;
    const float* X    = (m == 0) ? query : (m == 1) ? key : value;
    const float* W    = (m == 0) ? Wq    : (m == 1) ? Wk  : Wv;
    const float* bias = (m == 0) ? bq    : (m == 1) ? bk  : bv;
    const int t = threadIdx.x;

    // w~ = log2e * (1/sqrt(D) + wd + wsg + wtt)  -> ws tail (block 0)
    if (bx == 0 && t < 128) {
        ws[(size_t)4 * MATN + t] = LOG2E * (INV_SCALE + wd[t] + wsg[t] + wtt[t]);
    }

    const int cg = t & 31;   // cols: cg + 32*j
    const int rg = t >> 5;   // rows: rg*4 + i

    float acc[4][4];
    #pragma unroll
    for (int j = 0; j < 4; ++j) {
        float bj = bias[cg + 32 * j];
        #pragma unroll
        for (int i = 0; i < 4; ++i) acc[i][j] = bj;
    }

    const float4* Wsrc = (const float4*)W;
    const float4* Xsrc = (const float4*)X;

    for (int h = 0; h < 2; ++h) {            // K-dim halves (64 each)
        __syncthreads();
        #pragma unroll
        for (int j = 0; j < 8; ++j) {        // W half: 128 rows x 16 f4
            int g = t + j * 256;
            int c = g >> 4, f4 = g & 15;
            float4 v = Wsrc[c * 32 + h * 16 + f4];
            float* dst = &Wl[c * 66 + f4 * 4];
            *(float2*)dst       = make_float2(v.x, v.y);
            *(float2*)(dst + 2) = make_float2(v.z, v.w);
        }
        #pragma unroll
        for (int j = 0; j < 2; ++j) {        // X half: 32 rows x 16 f4
            int g = t + j * 256;
            int r = g >> 4, f4 = g & 15;
            float4 v = Xsrc[(r0 + r) * 32 + h * 16 + f4];
            float* dst = &Xl[r * 66 + f4 * 4];
            *(float2*)dst       = make_float2(v.x, v.y);
            *(float2*)(dst + 2) = make_float2(v.z, v.w);
        }
        __syncthreads();

        #pragma unroll 4
        for (int dg = 0; dg < 32; ++dg) {
            float2 bf[4];
            #pragma unroll
            for (int j = 0; j < 4; ++j)
                bf[j] = *(const float2*)&Wl[(cg + 32 * j) * 66 + 2 * dg];
            float2 af[4];
            #pragma unroll
            for (int i = 0; i < 4; ++i)
                af[i] = *(const float2*)&Xl[(rg * 4 + i) * 66 + 2 * dg];
            #pragma unroll
            for (int i = 0; i < 4; ++i)
                #pragma unroll
                for (int j = 0; j < 4; ++j)
                    acc[i][j] += af[i].x * bf[j].x + af[i].y * bf[j].y;
        }
    }

    if (m == 0) {
        float* oT = ws;                     // Tq
        float* oW = ws + (size_t)MATN;      // WTq = w~ * Tq
        float wc[4];
        #pragma unroll
        for (int j = 0; j < 4; ++j) {
            int c = cg + 32 * j;
            wc[j] = LOG2E * (INV_SCALE + wd[c] + wsg[c] + wtt[c]);
        }
        #pragma unroll
        for (int i = 0; i < 4; ++i) {
            int r = r0 + rg * 4 + i;
            #pragma unroll
            for (int j = 0; j < 4; ++j) {
                float z = acc[i][j];
                float e = fast_exp2(C1 * z);
                float th = (e - 1.0f) * fast_rcp(e + 1.0f);   // tanh(z)
                oT[(size_t)r * DD + cg + 32 * j] = th;
                oW[(size_t)r * DD + cg + 32 * j] = wc[j] * th;
            }
        }
    } else if (m == 1) {
        float* oK = ws + (size_t)2 * MATN;  // Tk
        #pragma unroll
        for (int i = 0; i < 4; ++i) {
            int r = r0 + rg * 4 + i;
            #pragma unroll
            for (int j = 0; j < 4; ++j) {
                float z = acc[i][j];
                float e = fast_exp2(C1 * z);
                oK[(size_t)r * DD + cg + 32 * j] = (e - 1.0f) * fast_rcp(e + 1.0f);
            }
        }
    } else {
        float* oV = ws + (size_t)3 * MATN;  // V
        #pragma unroll
        for (int i = 0; i < 4; ++i) {
            int r = r0 + rg * 4 + i;
            #pragma unroll
            for (int j = 0; j < 4; ++j)
                oV[(size_t)r * DD + cg + 32 * j] = acc[i][j];
        }
    }
}

// ---------------------------------------------------------------------------
// Attention main. 512 blocks x 512 threads (8 waves). Block = 32 q x k-quarter
// (2 tiles of 64 k). Wave = 4 consecutive q-rows. Per tile: stage Tk->[k][130];
// pass A lane-owns-k over all 128 d, Q-side fully wave-uniform (s_loads);
// fused pass B: lane = d-pair, V read from GLOBAL (coalesced f2, L1-shared
// across 8 waves), P via same-wave LDS rows. Partial o/psum -> f32 atomics.
// ---------------------------------------------------------------------------
__global__ __launch_bounds__(512, 4) void attn_kernel(
    const float* __restrict__ ws, float* __restrict__ out,
    float* __restrict__ psumG)
{
    __shared__ __align__(16) float Tkt[64 * 130];   // 33280 B
    __shared__ __align__(16) float Pt[8 * 4 * 64];  //  8192 B

    const float* Tq  = ws;
    const float* WTq = ws + (size_t)MATN;
    const float* Tk  = ws + (size_t)2 * MATN;
    const float* Vp  = ws + (size_t)3 * MATN;
    const float4* W4 = (const float4*)(ws + (size_t)4 * MATN);

    const int bx   = blockIdx.x;               // 512 blocks
    const int qblk = bx >> 2;                  // 0..127  (32 q each)
    const int kx   = bx & 3;                   // k-quarter (2 tiles of 64 k)
    const int b    = qblk >> 4;                // 16 q-blocks per batch
    const int wave = __builtin_amdgcn_readfirstlane((int)threadIdx.x >> 6);
    const int lane = threadIdx.x & 63;
    const int qa   = qblk * 32 + wave * 4;     // wave-uniform

    const float4* __restrict__ Tq4 = (const float4*)Tq;
    const float4* __restrict__ Wq4 = (const float4*)WTq;
    const float* __restrict__ Tkb = Tk + (size_t)b * (LL * DD);
    const float* __restrict__ Vb  = Vp + (size_t)b * (LL * DD);

    float2 o[4];
    float ps[4];
    #pragma unroll
    for (int qq = 0; qq < 4; ++qq) { o[qq] = make_float2(0.f, 0.f); ps[qq] = 0.f; }

    float* PtW = &Pt[wave * 256];

    for (int j = 0; j < 2; ++j) {
        const int tt = kx * 2 + j;
        __syncthreads();
        {   // stage Tk tile (64 k x 128 d), 2048 f4 over 512 thr = 4 each
            const float4* sK = (const float4*)(Tkb + (size_t)tt * 64 * DD);
            #pragma unroll
            for (int r = 0; r < 4; ++r) {
                int g = threadIdx.x + r * 512;     // 0..2047
                int row = g >> 5, c4 = g & 31;
                float4 v = sK[g];
                float* dst = &Tkt[row * 130 + c4 * 4];
                *(float2*)dst       = make_float2(v.x, v.y);
                *(float2*)(dst + 2) = make_float2(v.z, v.w);
            }
        }
        __syncthreads();

        // ---- pass A: s(qa..qa+3, k=lane) over all 128 d, dual accumulators
        float sA[4] = {0.f, 0.f, 0.f, 0.f};
        float sB[4] = {0.f, 0.f, 0.f, 0.f};
        const float* krow = &Tkt[lane * 130];
        #pragma unroll 2
        for (int i = 0; i < 32; ++i) {
            float4 w   = W4[i];                         // uniform -> s_load
            float2 k01 = *(const float2*)(krow + 4 * i);
            float2 k23 = *(const float2*)(krow + 4 * i + 2);
            float u0 = w.x * k01.x, u1 = w.y * k01.y;
            float u2 = w.z * k23.x, u3 = w.w * k23.y;
            #pragma unroll
            for (int qq = 0; qq < 4; ++qq) {
                float4 tq = Tq4[(size_t)(qa + qq) * 32 + i];  // uniform
                float4 aq = Wq4[(size_t)(qa + qq) * 32 + i];  // uniform
                float e0 = fmaf(tq.x, k01.x, 1.f), e1 = fmaf(tq.y, k01.y, 1.f);
                float e2 = fmaf(tq.z, k23.x, 1.f), e3 = fmaf(tq.w, k23.y, 1.f);
                float t0 = aq.x + u0, t1 = aq.y + u1;
                float t2 = aq.z + u2, t3 = aq.w + u3;
                float N01 = fmaf(t0, e1, t1 * e0);
                float N23 = fmaf(t2, e3, t3 * e2);
                sA[qq] = fmaf(N01, fast_rcp(e0 * e1), sA[qq]);
                sB[qq] = fmaf(N23, fast_rcp(e2 * e3), sB[qq]);
            }
        }
        float p0 = fast_exp2(sA[0] + sB[0]);
        float p1 = fast_exp2(sA[1] + sB[1]);
        float p2 = fast_exp2(sA[2] + sB[2]);
        float p3 = fast_exp2(sA[3] + sB[3]);
        PtW[lane]       = p0;
        PtW[64  + lane] = p1;
        PtW[128 + lane] = p2;
        PtW[192 + lane] = p3;
        ps[0] += p0; ps[1] += p1; ps[2] += p2; ps[3] += p3;

        // ---- pass B (same-wave Pt handoff; lane = d-pair; V from global)
        const float2* Vg = (const float2*)(Vb + (size_t)tt * 64 * DD);
        #pragma unroll
        for (int g = 0; g < 8; ++g) {
            float2 v[8];
            #pragma unroll
            for (int e = 0; e < 8; ++e)
                v[e] = Vg[(size_t)(8 * g + e) * 64 + lane];   // coalesced
            float4 pa0 = *(const float4*)&PtW[      8 * g];
            float4 pa1 = *(const float4*)&PtW[      8 * g + 4];
            float4 pb0 = *(const float4*)&PtW[64  + 8 * g];
            float4 pb1 = *(const float4*)&PtW[64  + 8 * g + 4];
            float4 pc0 = *(const float4*)&PtW[128 + 8 * g];
            float4 pc1 = *(const float4*)&PtW[128 + 8 * g + 4];
            float4 pd0 = *(const float4*)&PtW[192 + 8 * g];
            float4 pd1 = *(const float4*)&PtW[192 + 8 * g + 4];
            #pragma unroll
            for (int e = 0; e < 8; ++e) {
                float fa = (e < 4) ? ((const float*)&pa0)[e] : ((const float*)&pa1)[e - 4];
                float fb = (e < 4) ? ((const float*)&pb0)[e] : ((const float*)&pb1)[e - 4];
                float fc = (e < 4) ? ((const float*)&pc0)[e] : ((const float*)&pc1)[e - 4];
                float fd = (e < 4) ? ((const float*)&pd0)[e] : ((const float*)&pd1)[e - 4];
                o[0].x = fmaf(fa, v[e].x, o[0].x); o[0].y = fmaf(fa, v[e].y, o[0].y);
                o[1].x = fmaf(fb, v[e].x, o[1].x); o[1].y = fmaf(fb, v[e].y, o[1].y);
                o[2].x = fmaf(fc, v[e].x, o[2].x); o[2].y = fmaf(fc, v[e].y, o[2].y);
                o[3].x = fmaf(fd, v[e].x, o[3].x); o[3].y = fmaf(fd, v[e].y, o[3].y);
            }
        }
    }

    // psum: each lane holds the sum over its owned k's (distinct per lane)
    #pragma unroll
    for (int off = 32; off; off >>= 1) {
        ps[0] += __shfl_xor(ps[0], off);
        ps[1] += __shfl_xor(ps[1], off);
        ps[2] += __shfl_xor(ps[2], off);
        ps[3] += __shfl_xor(ps[3], off);
    }
    if (lane == 0) {
        atomicAdd(&psumG[qa + 0], ps[0]);
        atomicAdd(&psumG[qa + 1], ps[1]);
        atomicAdd(&psumG[qa + 2], ps[2]);
        atomicAdd(&psumG[qa + 3], ps[3]);
    }
    const int d2 = 2 * lane;
    #pragma unroll
    for (int qq = 0; qq < 4; ++qq) {
        atomicAdd(&out[(size_t)(qa + qq) * DD + d2],     o[qq].x);
        atomicAdd(&out[(size_t)(qa + qq) * DD + d2 + 1], o[qq].y);
    }
}

// ---------------------------------------------------------------------------
__global__ __launch_bounds__(256) void norm_kernel(
    float* __restrict__ out, const float* __restrict__ psumG)
{
    int t = blockIdx.x * 256 + threadIdx.x;    // 262144 float2s
    float2* o2 = (float2*)out;
    int q = t >> 6;
    float inv = fast_rcp(psumG[q]);
    float2 v = o2[t];
    o2[t] = make_float2(v.x * inv, v.y * inv);
}

// ---------------------------------------------------------------------------
extern "C" void kernel_launch(void* const* d_in, const int* in_sizes, int n_in,
                              void* d_out, int out_size, void* d_ws, size_t ws_size,
                              hipStream_t stream) {
    const float* query = (const float*)d_in[0];
    const float* key_  = (const float*)d_in[1];
    const float* value = (const float*)d_in[2];
    const float* Wq    = (const float*)d_in[3];
    const float* bq    = (const float*)d_in[4];
    const float* Wk    = (const float*)d_in[5];
    const float* bk    = (const float*)d_in[6];
    const float* Wv    = (const float*)d_in[7];
    const float* bv    = (const float*)d_in[8];
    const float* wd    = (const float*)d_in[9];
    // d_in[10]/[12]/[14] = b_delta/b_sigma/b_theta: softmax-invariant, dropped
    const float* wsg   = (const float*)d_in[11];
    const float* wtt   = (const float*)d_in[13];
    float* ws = (float*)d_ws;   // 4*MATN + 128 + 4096 floats ~ 8.4 MB
    float* psumG = ws + (size_t)4 * MATN + 128;
    float* out = (float*)d_out;

    hipMemsetAsync(out, 0, (size_t)out_size * sizeof(float), stream);
    hipMemsetAsync(psumG, 0, (size_t)NROW * sizeof(float), stream);
    proj_kernel<<<384, 256, 0, stream>>>(query, key_, value,
                                         Wq, bq, Wk, bk, Wv, bv,
                                         wd, wsg, wtt, ws);
    attn_kernel<<<512, 512, 0, stream>>>(ws, out, psumG);
    norm_kernel<<<1024, 256, 0, stream>>>(out, psumG);
}